// Round 11
// baseline (330.643 us; speedup 1.0000x reference)
//
#include <hip/hip_runtime.h>

#define NSTEPS 730
#define NGRID  10000
#define LENF   15
#define NEARZERO 1e-5f
#define KB 10            // steps per pipeline block
#define NBLK 73          // 730 = 73 * 10
#define NROUND (NBLK + 3)  // 76: B soils block m; C FIRs m-2, stores m-3

struct F3 { float p, t, e; };  // (prcp, tmean, pet), 12B

// 2-role pipeline (round-10 structure, one bug fixed).
// ROUND-10 BUG: dropped min(sw,1) on a false invariant "sm<=FC". Capillary
// adds to sm AFTER the FC clamp (sm = sm3 + cap; no re-clamp in the
// reference either), so sm can exceed FC when slz is large -> sw>1 ->
// negative sm1 -> absmax 12. RESTORED. The other cut is sound and kept:
// cap = C*slz*d <= slz (C<=1, d<=1, slz>=0) => min(slz, .) redundant.
//
// Structure rationale (rounds 0-9 evidence): every pipeline variant lands
// at 105-115us; B's soil chain ~230cy/step (~2300cy/round) vs measured
// ~3300cy/round => ~1000cy/round of A->B handoff + barrier overhead.
// Here the snow chain folds INTO the soil wave (executes inside the
// log/exp latency shadows, adds zero to the carried cycle), deleting the
// A->B LDS hop entirely:
//   Wave B (wid 0): reg-ring-3 input prefetch + snow + soil -> q LDS ring
//   Wave C (wid 1): 15-tap FIR + one-round-delayed stores
// q ring: 6 slots; __syncthreads() every 2 rounds only (write at round m,
// read at m+2: an odd-round barrier always separates; reuse at m+6).
__global__ __launch_bounds__(128, 1) void hbv_pipe2(const float* __restrict__ xp,
                                                    const float* __restrict__ ps,
                                                    float* __restrict__ out) {
    __shared__ float q_buf[6][KB][64];   // B -> C : q, 6-slot ring, 15360B

    const int lane = threadIdx.x & 63;
    const int wid  = threadIdx.x >> 6;
    int g = blockIdx.x * 64 + lane;
    g = (g < NGRID) ? g : (NGRID - 1);   // clamp: dup work, benign
    const int pb = g * 16;
    const F3* __restrict__ xv = (const F3*)xp;

    // ---- role B state ----
    float aTT = 0, aCFMAX = 0, aCFRxCFMAX = 0, aCWH = 0;
    float snow = NEARZERO, melt = NEARZERO;
    float bFC = 0, bBETA = 0, bB1 = 0, bBETAET = 0, bB2 = 0, bInvFC = 0,
          bC = 0, bPERC = 0, bK0 = 0, bK1 = 0, bK2 = 0, bUZL = 0;
    float sm = NEARZERO, suz = NEARZERO, slz = NEARZERO;
    F3 bufA[KB], bufB[KB], bufC[KB];     // reg ring, static names only
    // ---- role C state ----
    float w[LENF];
    float r[LENF - 1];
    float outvE[KB], outvO[KB];          // delayed-store double buffer

    if (wid == 0) {
        aTT        = ps[pb + 8]  * 5.0f - 2.5f;
        aCFMAX     = ps[pb + 9]  * 9.5f + 0.5f;
        aCFRxCFMAX = (ps[pb + 10] * 0.1f) * aCFMAX;
        aCWH       = ps[pb + 11] * 0.2f;
        bFC     = ps[pb + 1]  * 950.0f + 50.0f;
        bBETA   = ps[pb + 0]  * 5.0f   + 1.0f;
        float LP = ps[pb + 5] * 0.8f   + 0.2f;
        bBETAET = ps[pb + 12] * 4.7f   + 0.3f;
        bInvFC  = 1.0f / bFC;
        // fold the argument scaling into the log: log2(x/FC)=log2(x)-log2(FC)
        bB1 = -bBETA   * __builtin_amdgcn_logf(bFC);
        bB2 = -bBETAET * __builtin_amdgcn_logf(LP * bFC);
        bC   = ps[pb + 13];
        bPERC = ps[pb + 6] * 10.0f;
        bK0  = ps[pb + 2] * 0.85f  + 0.05f;
        bK1  = ps[pb + 3] * 0.49f  + 0.01f;
        bK2  = ps[pb + 4] * 0.199f + 0.001f;
        bUZL = ps[pb + 7] * 100.0f;
    } else {
        // routing weights; -lgamma(aa)-aa*log(theta) cancel under normalization
        const float LOG2E = 1.4426950408889634f;
        float aa    = fmaxf(ps[pb + 14] * 2.9f, 0.0f) + 0.1f;
        float theta = fmaxf(ps[pb + 15] * 6.5f, 0.0f) + 0.5f;
        float sc = LOG2E / theta, am1 = aa - 1.0f, wsum = 0.0f;
#pragma unroll
        for (int k = 0; k < LENF; ++k) {
            float tg = (float)k + 0.5f;
            w[k] = __builtin_amdgcn_exp2f(am1 * __builtin_amdgcn_logf(tg) - tg * sc);
            wsum += w[k];
        }
        float inv = 1.0f / wsum;
#pragma unroll
        for (int k = 0; k < LENF; ++k) w[k] *= inv;
#pragma unroll
        for (int j = 0; j < LENF - 1; ++j) r[j] = 0.0f;
    }

    auto LOADIN = [&](F3* buf, int blk) {
#pragma unroll
        for (int i = 0; i < KB; ++i)
            buf[i] = xv[(size_t)(blk * KB + i) * NGRID + g];
    };

    // snow + soil for one block; q written to the LDS ring slot b%6.
    // Snow's ~10-op chain executes under the soil log/exp latencies.
    auto SOIL = [&](const F3* in, int b) {
        float (*qp)[64] = q_buf[b % 6];
#pragma unroll
        for (int i = 0; i < KB; ++i) {
            float p = in[i].p, tm = in[i].t, pe = in[i].e;
            float dt = tm - aTT;
            float rain = (dt >= 0.0f) ? p : 0.0f;
            float mm = fmaxf(aCFMAX * dt, 0.0f);
            float rr = fmaxf(-aCFRxCFMAX * dt, 0.0f);
            snow += p - rain;
            float mq = fminf(mm, snow);
            melt += mq; snow -= mq;
            float refr = fminf(rr, melt);
            snow += refr; melt -= refr;
            float tosoil = fmaxf(fmaf(-aCWH, snow, melt), 0.0f);
            melt -= tosoil;
            float rt = rain + tosoil;

            // soil/runoff: the irreducible carried cycle
            float l1  = __builtin_amdgcn_logf(sm);
            float sw  = fminf(__builtin_amdgcn_exp2f(fmaf(bBETA, l1, bB1)), 1.0f);
            float smp = sm + rt;
            float sm1 = fmaf(-rt, sw, smp);
            float rch = rt * sw;
            float sm2 = fminf(sm1, bFC);
            float exc = fmaxf(sm1 - bFC, 0.0f);
            float l2  = __builtin_amdgcn_logf(sm2);
            float ef  = fminf(__builtin_amdgcn_exp2f(fmaf(bBETAET, l2, bB2)), 1.0f);
            float sm3 = fmaxf(fmaf(-pe, ef, sm2), NEARZERO);
            float d   = fmaxf(fmaf(-bInvFC, sm3, 1.0f), 0.0f);
            float cz  = bC * slz;
            float cap = cz * d;               // == min(slz, cz*d): C<=1, d<=1
            sm = sm3 + cap;
            float slz1 = fmaxf(slz - cap, NEARZERO);
            float su1 = suz + rch + exc;
            float pa  = fminf(su1, bPERC);
            float su2 = su1 - pa;
            float q0  = bK0 * fmaxf(su2 - bUZL, 0.0f);
            float su3 = su2 - q0;
            float q1  = bK1 * su3;
            suz = su3 - q1;
            float sl2 = slz1 + pa;
            float q2  = bK2 * sl2;
            slz = sl2 - q2;
            qp[i][lane] = (q0 + q1) + q2;
        }
    };
    auto FIR = [&](float* ov, int b) {
        float (*qp)[64] = q_buf[b % 6];
        float qv[KB];
#pragma unroll
        for (int i = 0; i < KB; ++i) qv[i] = qp[i][lane];
#pragma unroll
        for (int i = 0; i < KB; ++i) {
            float q = qv[i];
            ov[i] = fmaf(w[0], q, r[0]);
#pragma unroll
            for (int j = 0; j < LENF - 2; ++j)
                r[j] = fmaf(w[j + 1], q, r[j + 1]);
            r[LENF - 2] = w[LENF - 1] * q;
        }
    };
    auto STORE = [&](const float* ov, int b) {
#pragma unroll
        for (int i = 0; i < KB; ++i)
            out[(size_t)(b * KB + i) * NGRID + g] = ov[i];
    };

    // prologue: blocks 0 and 1 in flight (compiler auto-waits at first use)
    if (wid == 0) {
        LOADIN(bufA, 0);
        LOADIN(bufB, 1);
    }

    for (int m = 0; m < NROUND; ++m) {
        if (wid == 0) {
            const int ph = m % 3;   // block m lives in slot m%3
            // issue block m+2's loads first (consumed 2 rounds later)
            if (m + 2 < NBLK) {
                if (ph == 0)      LOADIN(bufC, m + 2);   // slot (m+2)%3 == 2
                else if (ph == 1) LOADIN(bufA, m + 2);   // slot 0
                else              LOADIN(bufB, m + 2);   // slot 1
            }
            // snow+soil on block m (loaded 2 rounds ago)
            if (m < NBLK) {
                if (ph == 0)      SOIL(bufA, m);
                else if (ph == 1) SOIL(bufB, m);
                else              SOIL(bufC, m);
            }
        } else {
            // store block m-3 first (regs written last round; fire-and-forget)
            if (m >= 3 && m <= NBLK + 2) {
                const int bs = m - 3;
                if ((bs & 1) == 0) STORE(outvE, bs);
                else               STORE(outvO, bs);
            }
            // FIR block m-2 into the other parity buffer
            if (m >= 2 && m <= NBLK + 1) {
                const int b = m - 2;
                if ((b & 1) == 0) FIR(outvE, b);
                else              FIR(outvO, b);
            }
        }
        if (m & 1) __syncthreads();   // barrier every 2 rounds (ring-6 safe)
    }
}

extern "C" void kernel_launch(void* const* d_in, const int* in_sizes, int n_in,
                              void* d_out, int out_size, void* d_ws, size_t ws_size,
                              hipStream_t stream) {
    const float* x_phy      = (const float*)d_in[0]; // f32 (730,10000,3)
    const float* phy_static = (const float*)d_in[1]; // f32 (10000,16)
    float* out = (float*)d_out;                      // f32 (730,10000)

    int nwg = (NGRID + 63) / 64;  // 157 workgroups x 128 threads (2 waves)
    hbv_pipe2<<<nwg, 128, 0, stream>>>(x_phy, phy_static, out);
}